// Round 1
// baseline (6605.496 us; speedup 1.0000x reference)
//
#include <hip/hip_runtime.h>
#include <hip/hip_bf16.h>
#include <cmath>

// Problem constants (Swin3D block, B=4, C=96, res 16x56x56, window 2x7x7, shift 1x3x3)
#define C_DIM 96
#define N_HEADS 4
#define D_HEAD 24
#define RES_D 16
#define RES_H 56
#define RES_W 56
#define BATCH 4
#define HIDDEN 384
#define SPATIAL (RES_D*RES_H*RES_W)      // 50176
#define NTOK (BATCH*SPATIAL)             // 200704
#define NWIN 98                          // 2*7*7 tokens per window
#define NWIN_TOT 2048                    // 4 * 8*8*8 windows
#define EPS_LN 1e-5f
#define QSCALE 0.2041241452319315f       // 1/sqrt(24)

__device__ __forceinline__ float wave_reduce_sum(float v) {
#pragma unroll
    for (int off = 32; off > 0; off >>= 1) v += __shfl_xor(v, off, 64);
    return v;
}
__device__ __forceinline__ float wave_reduce_max(float v) {
#pragma unroll
    for (int off = 32; off > 0; off >>= 1) v = fmaxf(v, __shfl_xor(v, off, 64));
    return v;
}

// ---------------- Kernel 0: (B,C,S) -> (B,S,C) channels-last transpose ----------------
__global__ __launch_bounds__(256) void k_transpose_in(const float* __restrict__ x,
                                                      float* __restrict__ xl) {
    __shared__ float tile[32][33];
    const int b = blockIdx.z;
    const int s0 = blockIdx.x * 32;
    const int c0 = blockIdx.y * 32;
    const float* xb = x + (size_t)b * C_DIM * SPATIAL;
    float* xlb = xl + (size_t)b * SPATIAL * C_DIM;
    const int ts = threadIdx.x;   // 0..31
    const int tc = threadIdx.y;   // 0..7
#pragma unroll
    for (int i = 0; i < 32; i += 8)
        tile[tc + i][ts] = xb[(size_t)(c0 + tc + i) * SPATIAL + s0 + ts];
    __syncthreads();
#pragma unroll
    for (int i = 0; i < 32; i += 8)
        xlb[(size_t)(s0 + tc + i) * C_DIM + c0 + ts] = tile[ts][tc + i];
}

// ---------------- Kernel 1: per-window LN1 + QKV + attention + proj + residual ----------------
// One workgroup (256 threads) per window. LDS ~150 KiB -> 1 WG/CU (baseline; optimize later).
__global__ __launch_bounds__(256) void k_win_attn(
    const float* __restrict__ xl, float* __restrict__ xl2,
    const float* __restrict__ g1, const float* __restrict__ b1,
    const float* __restrict__ qkv_w, const float* __restrict__ qkv_b,
    const float* __restrict__ proj_w, const float* __restrict__ proj_b,
    const float* __restrict__ rpb) {
    // stride 97 breaks the 96-float (bank-aligned) stride; scores use stride 99
    __shared__ float s_q[NWIN * 97];
    __shared__ float s_k[NWIN * 97];
    __shared__ float s_v[NWIN * 97];
    __shared__ float s_xs[NWIN * 99];   // LN'd x (stride 97), later P scores (stride 99)
    __shared__ int s_gtok[NWIN];
    __shared__ int s_reg[NWIN];

    const int tid = threadIdx.x;
    const int lane = tid & 63;
    const int wave = tid >> 6;
    const int wid = blockIdx.x;
    const int b = wid >> 9;          // 512 windows per batch
    const int rem = wid & 511;
    const int wdi = rem >> 6;        // window index along D (0..7)
    const int whi = (rem >> 3) & 7;  // along H
    const int wwi = rem & 7;         // along W

    // token -> global location (+ shift-mask region id)
    if (tid < NWIN) {
        const int n = tid;
        const int dz = n / 49, r = n % 49, hy = r / 7, wx = r % 7;
        const int rd = wdi * 2 + dz, rh = whi * 7 + hy, rw = wwi * 7 + wx;
        int od = rd + 1; if (od >= RES_D) od -= RES_D;   // reverse of roll(-1)
        int oh = rh + 3; if (oh >= RES_H) oh -= RES_H;
        int ow = rw + 3; if (ow >= RES_W) ow -= RES_W;
        s_gtok[n] = ((b * RES_D + od) * RES_H + oh) * RES_W + ow;
        const int gd = (rd < 14) ? 0 : (rd < 15 ? 1 : 2);
        const int gh = (rh < 49) ? 0 : (rh < 53 ? 1 : 2);
        const int gw = (rw < 49) ? 0 : (rw < 53 ? 1 : 2);
        s_reg[n] = gd * 9 + gh * 3 + gw;
    }
    __syncthreads();

    // LN1 -> s_xs (stride 97). One wave per token.
    for (int n = wave; n < NWIN; n += 4) {
        const size_t base = (size_t)s_gtok[n] * C_DIM;
        const float v0 = xl[base + lane];
        const float v1 = (lane < 32) ? xl[base + 64 + lane] : 0.0f;
        const float mu = wave_reduce_sum(v0 + v1) * (1.0f / 96.0f);
        const float d0 = v0 - mu;
        const float d1 = (lane < 32) ? (v1 - mu) : 0.0f;
        const float var = wave_reduce_sum(d0 * d0 + d1 * d1) * (1.0f / 96.0f);
        const float rstd = rsqrtf(var + EPS_LN);
        s_xs[n * 97 + lane] = d0 * rstd * g1[lane] + b1[lane];
        if (lane < 32) s_xs[n * 97 + 64 + lane] = d1 * rstd * g1[64 + lane] + b1[64 + lane];
    }
    __syncthreads();

    // QKV: (98x96)@(96x288). j layout = (qkv_sel, head, dh).
    for (int idx = tid; idx < NWIN * 288; idx += 256) {
        const int tok = idx / 288, j = idx % 288;
        float acc = qkv_b[j];
        const float* xr = &s_xs[tok * 97];
#pragma unroll 8
        for (int c = 0; c < 96; ++c) acc = fmaf(xr[c], qkv_w[c * 288 + j], acc);
        if (j < 96)       s_q[tok * 97 + j] = acc * QSCALE;
        else if (j < 192) s_k[tok * 97 + (j - 96)] = acc;
        else              s_v[tok * 97 + (j - 192)] = acc;
    }
    __syncthreads();

    // per-head: scores(+rpb+mask) -> softmax -> P@V (output overwrites q columns)
    for (int h = 0; h < 4; ++h) {
        const int hb = h * 24;
        for (int idx = tid; idx < NWIN * NWIN; idx += 256) {
            const int n = idx / NWIN, m = idx % NWIN;
            float acc = 0.0f;
            const float* qr = &s_q[n * 97 + hb];
            const float* kr = &s_k[m * 97 + hb];
#pragma unroll
            for (int d = 0; d < 24; ++d) acc = fmaf(qr[d], kr[d], acc);
            // relative position bias (table idx computed in registers)
            const int dzn = n / 49, rn = n % 49, hyn = rn / 7, wxn = rn % 7;
            const int dzm = m / 49, rm = m % 49, hym = rm / 7, wxm = rm % 7;
            const int ridx = (dzn - dzm + 1) * 169 + (hyn - hym + 6) * 13 + (wxn - wxm + 6);
            acc += rpb[ridx * 4 + h];
            if (s_reg[n] != s_reg[m]) acc -= 100.0f;   // shift mask
            s_xs[n * 99 + m] = acc;
        }
        __syncthreads();
        // row softmax (one wave per row)
        for (int n = wave; n < NWIN; n += 4) {
            const float a0 = s_xs[n * 99 + lane];
            const float a1 = (lane < 34) ? s_xs[n * 99 + 64 + lane] : -3.0e38f;
            const float mx = wave_reduce_max(fmaxf(a0, a1));
            const float e0 = __expf(a0 - mx);
            const float e1 = (lane < 34) ? __expf(a1 - mx) : 0.0f;
            const float inv = 1.0f / wave_reduce_sum(e0 + e1);
            s_xs[n * 99 + lane] = e0 * inv;
            if (lane < 34) s_xs[n * 99 + 64 + lane] = e1 * inv;
        }
        __syncthreads();
        // P @ V -> overwrite s_q head columns (q for this head is consumed)
        for (int idx = tid; idx < NWIN * 24; idx += 256) {
            const int n = idx / 24, d = idx % 24;
            float acc = 0.0f;
            const float* pr = &s_xs[n * 99];
#pragma unroll 7
            for (int m = 0; m < NWIN; ++m) acc = fmaf(pr[m], s_v[m * 97 + hb + d], acc);
            s_q[n * 97 + hb + d] = acc;
        }
        __syncthreads();
    }

    // proj + residual; write xl2 at the original (pre-roll) token -> no scatter conflicts
    for (int idx = tid; idx < NWIN * 96; idx += 256) {
        const int n = idx / 96, c = idx % 96;
        float acc = proj_b[c];
        const float* orow = &s_q[n * 97];
#pragma unroll 8
        for (int cc = 0; cc < 96; ++cc) acc = fmaf(orow[cc], proj_w[cc * 96 + c], acc);
        const size_t base = (size_t)s_gtok[n] * C_DIM + c;
        xl2[base] = xl[base] + acc;
    }
}

// ---------------- Kernel 2: LN2 + FC1 + GELU + FC2 + residual + transpose-out ----------------
__global__ __launch_bounds__(256) void k_ffn(
    const float* __restrict__ xl2, float* __restrict__ out,
    const float* __restrict__ g2, const float* __restrict__ b2,
    const float* __restrict__ fc1_w, const float* __restrict__ fc1_b,
    const float* __restrict__ fc2_w, const float* __restrict__ fc2_b) {
    __shared__ float s_h[32 * 97];
    __shared__ float s_g[32 * 385];
    const int tid = threadIdx.x, lane = tid & 63, wave = tid >> 6;
    const int t0 = blockIdx.x * 32;

    for (int n = wave; n < 32; n += 4) {
        const size_t base = (size_t)(t0 + n) * C_DIM;
        const float v0 = xl2[base + lane];
        const float v1 = (lane < 32) ? xl2[base + 64 + lane] : 0.0f;
        const float mu = wave_reduce_sum(v0 + v1) * (1.0f / 96.0f);
        const float d0 = v0 - mu;
        const float d1 = (lane < 32) ? (v1 - mu) : 0.0f;
        const float var = wave_reduce_sum(d0 * d0 + d1 * d1) * (1.0f / 96.0f);
        const float rstd = rsqrtf(var + EPS_LN);
        s_h[n * 97 + lane] = d0 * rstd * g2[lane] + b2[lane];
        if (lane < 32) s_h[n * 97 + 64 + lane] = d1 * rstd * g2[64 + lane] + b2[64 + lane];
    }
    __syncthreads();
    // FC1 + exact GELU
    for (int idx = tid; idx < 32 * 384; idx += 256) {
        const int tok = idx / 384, j = idx % 384;
        float acc = fc1_b[j];
        const float* hr = &s_h[tok * 97];
#pragma unroll 8
        for (int c = 0; c < 96; ++c) acc = fmaf(hr[c], fc1_w[c * 384 + j], acc);
        s_g[tok * 385 + j] = 0.5f * acc * (1.0f + erff(acc * 0.70710678118654752f));
    }
    __syncthreads();
    // FC2 + residual; write channels-first output (c slow, tok fast -> coalesced 128B runs)
    for (int idx = tid; idx < 32 * 96; idx += 256) {
        const int c = idx >> 5, tok = idx & 31;
        float acc = fc2_b[c];
        const float* gr = &s_g[tok * 385];
#pragma unroll 8
        for (int j = 0; j < 384; ++j) acc = fmaf(gr[j], fc2_w[j * 96 + c], acc);
        const int gt = t0 + tok;
        acc += xl2[(size_t)gt * C_DIM + c];
        const int bb = gt / SPATIAL, s = gt % SPATIAL;
        out[((size_t)bb * C_DIM + c) * SPATIAL + s] = acc;
    }
}

extern "C" void kernel_launch(void* const* d_in, const int* in_sizes, int n_in,
                              void* d_out, int out_size, void* d_ws, size_t ws_size,
                              hipStream_t stream) {
    const float* x      = (const float*)d_in[0];
    const float* g1     = (const float*)d_in[1];
    const float* be1    = (const float*)d_in[2];
    const float* g2     = (const float*)d_in[3];
    const float* be2    = (const float*)d_in[4];
    const float* qkv_w  = (const float*)d_in[5];
    const float* qkv_b  = (const float*)d_in[6];
    const float* proj_w = (const float*)d_in[7];
    const float* proj_b = (const float*)d_in[8];
    const float* rpb    = (const float*)d_in[9];
    const float* fc1_w  = (const float*)d_in[10];
    const float* fc1_b  = (const float*)d_in[11];
    const float* fc2_w  = (const float*)d_in[12];
    const float* fc2_b  = (const float*)d_in[13];
    float* out = (float*)d_out;

    // workspace: xl (channels-last input) + xl2 (post-attention), 77 MB each
    float* xl  = (float*)d_ws;
    float* xl2 = xl + (size_t)NTOK * C_DIM;

    k_transpose_in<<<dim3(SPATIAL / 32, C_DIM / 32, BATCH), dim3(32, 8), 0, stream>>>(x, xl);
    k_win_attn<<<NWIN_TOT, 256, 0, stream>>>(xl, xl2, g1, be1, qkv_w, qkv_b, proj_w, proj_b, rpb);
    k_ffn<<<NTOK / 32, 256, 0, stream>>>(xl2, out, g2, be2, fc1_w, fc1_b, fc2_w, fc2_b);
}

// Round 2
// 543.355 us; speedup vs baseline: 12.1569x; 12.1569x over previous
//
#include <hip/hip_runtime.h>
#include <hip/hip_bf16.h>
#include <cmath>

#define C_DIM 96
#define RES_D 16
#define RES_H 56
#define RES_W 56
#define BATCH 4
#define SPATIAL (RES_D*RES_H*RES_W)      // 50176
#define NTOK (BATCH*SPATIAL)             // 200704
#define NWIN_TOT 2048
#define EPS_LN 1e-5f
#define QSCALE 0.2041241452319315f       // 1/sqrt(24)

#define MPAD 128        // window tokens padded 98 -> 128
#define SXA 136         // LDS row stride (bf16 elems) for attn buffers

typedef float f32x4 __attribute__((ext_vector_type(4)));
typedef short s16x8 __attribute__((ext_vector_type(8)));
typedef unsigned short u16;

__device__ __forceinline__ u16 f2bf(float f) {
    unsigned u = __float_as_uint(f);
    u = (u + 0x7FFF + ((u >> 16) & 1)) >> 16;
    return (u16)u;
}

__device__ __forceinline__ float wave_reduce_sum(float v) {
#pragma unroll
    for (int off = 32; off > 0; off >>= 1) v += __shfl_xor(v, off, 64);
    return v;
}

// ---------------- prep: bf16-transpose weights + dense rpb matrix ----------------
// wq[288][96], wp[96][96], w1[384][96], w2[96][384] (bf16, [N][K]); rpbm f32 [4][128][128]
__global__ __launch_bounds__(256) void k_prep(
    const float* __restrict__ qkv_w, const float* __restrict__ proj_w,
    const float* __restrict__ fc1_w, const float* __restrict__ fc2_w,
    const float* __restrict__ rpb_table,
    u16* __restrict__ wq, u16* __restrict__ wp, u16* __restrict__ w1,
    u16* __restrict__ w2, float* __restrict__ rpbm) {
    int i = blockIdx.x * 256 + threadIdx.x;
    if (i < 27648) {
        int j = i / 96, c = i % 96;
        wq[i] = f2bf(qkv_w[c * 288 + j]);
    } else if (i < 36864) {
        int t = i - 27648; int j = t / 96, c = t % 96;
        wp[t] = f2bf(proj_w[c * 96 + j]);
    } else if (i < 73728) {
        int t = i - 36864; int j = t / 96, c = t % 96;
        w1[t] = f2bf(fc1_w[c * 384 + j]);
    } else if (i < 110592) {
        int t = i - 73728; int c = t / 384, j = t % 384;
        w2[t] = f2bf(fc2_w[j * 96 + c]);
    } else if (i < 176128) {
        int t = i - 110592;
        int h = t / 16384, r = t % 16384, n = r / 128, m = r % 128;
        float v = 0.0f;
        if (n < 98 && m < 98) {
            int dzn = n / 49, rn = n % 49, hyn = rn / 7, wxn = rn % 7;
            int dzm = m / 49, rm = m % 49, hym = rm / 7, wxm = rm % 7;
            int ridx = (dzn - dzm + 1) * 169 + (hyn - hym + 6) * 13 + (wxn - wxm + 6);
            v = rpb_table[ridx * 4 + h];
        }
        rpbm[t] = v;
    }
}

// ---------------- (B,C,S) -> (B,S,C) transpose ----------------
__global__ __launch_bounds__(256) void k_transpose_in(const float* __restrict__ x,
                                                      float* __restrict__ xl) {
    __shared__ float tile[32][33];
    const int b = blockIdx.z;
    const int s0 = blockIdx.x * 32;
    const int c0 = blockIdx.y * 32;
    const float* xb = x + (size_t)b * C_DIM * SPATIAL;
    float* xlb = xl + (size_t)b * SPATIAL * C_DIM;
    const int ts = threadIdx.x, tc = threadIdx.y;
#pragma unroll
    for (int i = 0; i < 32; i += 8)
        tile[tc + i][ts] = xb[(size_t)(c0 + tc + i) * SPATIAL + s0 + ts];
    __syncthreads();
#pragma unroll
    for (int i = 0; i < 32; i += 8)
        xlb[(size_t)(s0 + tc + i) * C_DIM + c0 + ts] = tile[ts][tc + i];
}

// ---------------- per-window attention, MFMA bf16 ----------------
__global__ __launch_bounds__(512) void k_win_attn(
    const float* __restrict__ xl, float* __restrict__ xl2,
    const float* __restrict__ g1, const float* __restrict__ b1,
    const u16* __restrict__ wqkv, const float* __restrict__ qkv_b,
    const u16* __restrict__ wproj, const float* __restrict__ proj_b,
    const float* __restrict__ rpbm) {
    __shared__ u16 s_a[MPAD * SXA];   // LN'd x, later P
    __shared__ u16 s_q[MPAD * SXA];   // q (per-head 32-col blocks), later O (96 packed)
    __shared__ u16 s_k[MPAD * SXA];   // k (per-head 32-col blocks)
    __shared__ u16 s_vt[MPAD * SXA];  // v transposed: [h*32+d][tok]
    __shared__ int s_gtok[MPAD];
    __shared__ int s_reg[MPAD];

    const int tid = threadIdx.x;
    const int lane = tid & 63;
    const int wave = tid >> 6;          // 0..7, owns M-tile `wave`
    const int g4 = lane >> 4;           // 0..3
    const int c16 = lane & 15;          // 0..15

    const int wid = blockIdx.x;
    const int b = wid >> 9;
    const int rem = wid & 511;
    const int wdi = rem >> 6, whi = (rem >> 3) & 7, wwi = rem & 7;

    // zero-fill bf16 buffers (provides all k/d/row padding)
    {
        unsigned* za = (unsigned*)s_a;  unsigned* zq = (unsigned*)s_q;
        unsigned* zk = (unsigned*)s_k;  unsigned* zv = (unsigned*)s_vt;
        for (int i = tid; i < MPAD * SXA / 2; i += 512) { za[i] = 0u; zq[i] = 0u; zk[i] = 0u; zv[i] = 0u; }
    }
    if (tid < MPAD) {
        if (tid < 98) {
            const int n = tid;
            const int dz = n / 49, r = n % 49, hy = r / 7, wx = r % 7;
            const int rd = wdi * 2 + dz, rh = whi * 7 + hy, rw = wwi * 7 + wx;
            int od = rd + 1; if (od >= RES_D) od -= RES_D;
            int oh = rh + 3; if (oh >= RES_H) oh -= RES_H;
            int ow = rw + 3; if (ow >= RES_W) ow -= RES_W;
            s_gtok[n] = ((b * RES_D + od) * RES_H + oh) * RES_W + ow;
            const int gd = (rd < 14) ? 0 : (rd < 15 ? 1 : 2);
            const int gh = (rh < 49) ? 0 : (rh < 53 ? 1 : 2);
            const int gw = (rw < 49) ? 0 : (rw < 53 ? 1 : 2);
            s_reg[n] = gd * 9 + gh * 3 + gw;
        } else { s_gtok[tid] = 0; s_reg[tid] = -1; }
    }
    __syncthreads();

    // LN1 -> s_a bf16 (one wave per token)
    for (int n = wave; n < 98; n += 8) {
        const size_t base = (size_t)s_gtok[n] * C_DIM;
        const float v0 = xl[base + lane];
        const float v1 = (lane < 32) ? xl[base + 64 + lane] : 0.0f;
        const float mu = wave_reduce_sum(v0 + v1) * (1.0f / 96.0f);
        const float d0 = v0 - mu;
        const float d1 = (lane < 32) ? (v1 - mu) : 0.0f;
        const float var = wave_reduce_sum(d0 * d0 + d1 * d1) * (1.0f / 96.0f);
        const float rstd = rsqrtf(var + EPS_LN);
        s_a[n * SXA + lane] = f2bf(d0 * rstd * g1[lane] + b1[lane]);
        if (lane < 32) s_a[n * SXA + 64 + lane] = f2bf(d1 * rstd * g1[64 + lane] + b1[64 + lane]);
    }
    __syncthreads();

    // QKV: rows of own M-tile, 18 N-tiles, K=96 (3 steps)
    const int mt = wave;
    {
        const int j = 0;
        (void)j;
    }
#pragma unroll 1
    for (int nt = 0; nt < 18; ++nt) {
        f32x4 acc = {0.f, 0.f, 0.f, 0.f};
#pragma unroll
        for (int ks = 0; ks < 3; ++ks) {
            s16x8 a = *(const s16x8*)(&s_a[(mt * 16 + c16) * SXA + ks * 32 + g4 * 8]);
            s16x8 bw = *(const s16x8*)(wqkv + (size_t)(nt * 16 + c16) * 96 + ks * 32 + g4 * 8);
            acc = __builtin_amdgcn_mfma_f32_16x16x32_bf16(a, bw, acc, 0, 0, 0);
        }
        const int jj = nt * 16 + c16;          // 0..287
        const int sel = jj / 96, j96 = jj % 96;
        const int h = j96 / 24, d = j96 % 24;
        const float bias = qkv_b[jj];
#pragma unroll
        for (int r = 0; r < 4; ++r) {
            const int row = mt * 16 + g4 * 4 + r;
            const float v = acc[r] + bias;
            if (sel == 0)      s_q[row * SXA + h * 32 + d] = f2bf(v * QSCALE);
            else if (sel == 1) s_k[row * SXA + h * 32 + d] = f2bf(v);
            else               s_vt[(h * 32 + d) * SXA + row] = f2bf(v);
        }
    }
    __syncthreads();

    // heads: scores -> softmax (in-register) -> P to LDS -> PV (O in registers)
    f32x4 og[4][2];
#pragma unroll
    for (int h = 0; h < 4; ++h) {
        f32x4 sc[8];
        const s16x8 aq = *(const s16x8*)(&s_q[(mt * 16 + c16) * SXA + h * 32 + g4 * 8]);
#pragma unroll
        for (int nt = 0; nt < 8; ++nt) {
            s16x8 bk = *(const s16x8*)(&s_k[(nt * 16 + c16) * SXA + h * 32 + g4 * 8]);
            f32x4 z = {0.f, 0.f, 0.f, 0.f};
            sc[nt] = __builtin_amdgcn_mfma_f32_16x16x32_bf16(aq, bk, z, 0, 0, 0);
        }
        const float* rh = rpbm + h * 16384;
        const int rbase = mt * 16 + g4 * 4;
        const int rg0 = s_reg[rbase], rg1 = s_reg[rbase + 1], rg2 = s_reg[rbase + 2], rg3 = s_reg[rbase + 3];
        const int rgs[4] = {rg0, rg1, rg2, rg3};
        float mx[4] = {-3.0e38f, -3.0e38f, -3.0e38f, -3.0e38f};
#pragma unroll
        for (int nt = 0; nt < 8; ++nt) {
            const int col = nt * 16 + c16;
            const int creg = s_reg[col];
#pragma unroll
            for (int r = 0; r < 4; ++r) {
                float s = sc[nt][r] + rh[(rbase + r) * 128 + col];
                if (col >= 98) s = -30000.0f;
                else if (rgs[r] != creg) s -= 100.0f;
                sc[nt][r] = s;
                mx[r] = fmaxf(mx[r], s);
            }
        }
#pragma unroll
        for (int r = 0; r < 4; ++r) {
#pragma unroll
            for (int m = 1; m <= 8; m <<= 1) mx[r] = fmaxf(mx[r], __shfl_xor(mx[r], m, 64));
        }
        float sm[4] = {0.f, 0.f, 0.f, 0.f};
#pragma unroll
        for (int nt = 0; nt < 8; ++nt) {
#pragma unroll
            for (int r = 0; r < 4; ++r) {
                const float e = __expf(sc[nt][r] - mx[r]);
                sc[nt][r] = e;
                sm[r] += e;
            }
        }
#pragma unroll
        for (int r = 0; r < 4; ++r) {
#pragma unroll
            for (int m = 1; m <= 8; m <<= 1) sm[r] += __shfl_xor(sm[r], m, 64);
            sm[r] = 1.0f / sm[r];
        }
#pragma unroll
        for (int nt = 0; nt < 8; ++nt) {
#pragma unroll
            for (int r = 0; r < 4; ++r)
                s_a[(rbase + r) * SXA + nt * 16 + c16] = f2bf(sc[nt][r] * sm[r]);
        }
        // PV: A=P (own rows), B=V^T
#pragma unroll
        for (int dt = 0; dt < 2; ++dt) {
            f32x4 acc = {0.f, 0.f, 0.f, 0.f};
#pragma unroll
            for (int ks = 0; ks < 4; ++ks) {
                s16x8 ap = *(const s16x8*)(&s_a[(mt * 16 + c16) * SXA + ks * 32 + g4 * 8]);
                s16x8 bv = *(const s16x8*)(&s_vt[(h * 32 + dt * 16 + c16) * SXA + ks * 32 + g4 * 8]);
                acc = __builtin_amdgcn_mfma_f32_16x16x32_bf16(ap, bv, acc, 0, 0, 0);
            }
            og[h][dt] = acc;
        }
    }
    __syncthreads();

    // store O (packed 96 cols) into s_q rows of own M-tile
#pragma unroll
    for (int h = 0; h < 4; ++h) {
#pragma unroll
        for (int dt = 0; dt < 2; ++dt) {
            const int d = dt * 16 + c16;
            if (d < 24) {
#pragma unroll
                for (int r = 0; r < 4; ++r)
                    s_q[(mt * 16 + g4 * 4 + r) * SXA + h * 24 + d] = f2bf(og[h][dt][r]);
            }
        }
    }
    __syncthreads();

    // proj + residual -> xl2
#pragma unroll 1
    for (int nt = 0; nt < 6; ++nt) {
        f32x4 acc = {0.f, 0.f, 0.f, 0.f};
#pragma unroll
        for (int ks = 0; ks < 3; ++ks) {
            s16x8 a = *(const s16x8*)(&s_q[(mt * 16 + c16) * SXA + ks * 32 + g4 * 8]);
            s16x8 bw = *(const s16x8*)(wproj + (size_t)(nt * 16 + c16) * 96 + ks * 32 + g4 * 8);
            acc = __builtin_amdgcn_mfma_f32_16x16x32_bf16(a, bw, acc, 0, 0, 0);
        }
        const int col = nt * 16 + c16;
        const float pb = proj_b[col];
#pragma unroll
        for (int r = 0; r < 4; ++r) {
            const int row = mt * 16 + g4 * 4 + r;
            if (row < 98) {
                const size_t base = (size_t)s_gtok[row] * C_DIM + col;
                xl2[base] = xl[base] + acc[r] + pb;
            }
        }
    }
}

// ---------------- FFN: LN2 + FC1 + GELU + FC2 + residual + transposed out ----------------
// 32 tokens per block, 256 threads (4 waves). LDS ~37.9 KB -> 4 WG/CU.
__global__ __launch_bounds__(256) void k_ffn(
    const float* __restrict__ xl2, float* __restrict__ out,
    const float* __restrict__ g2, const float* __restrict__ b2,
    const u16* __restrict__ w1, const float* __restrict__ fc1_b,
    const u16* __restrict__ w2, const float* __restrict__ fc2_b) {
    __shared__ char smem[25088 + 12800];
    u16* s_g = (u16*)smem;                    // [32][392] bf16 (25088 B)
    u16* s_h = (u16*)(smem + 25088);          // [32][104] bf16 (6656 B), dead after FC1
    float* s_res = (float*)(smem + 25088);    // [32][100] f32 (12800 B), aliases s_h

    const int tid = threadIdx.x;
    const int lane = tid & 63;
    const int wave = tid >> 6;       // 0..3
    const int g4 = lane >> 4, c16 = lane & 15;
    const int mt = wave & 1;         // M-tile (2 x 16 rows)
    const int nh = wave >> 1;        // N-half
    const int t0 = blockIdx.x * 32;

    // LN2 -> s_h
    for (int n = wave; n < 32; n += 4) {
        const size_t base = (size_t)(t0 + n) * C_DIM;
        const float v0 = xl2[base + lane];
        const float v1 = (lane < 32) ? xl2[base + 64 + lane] : 0.0f;
        const float mu = wave_reduce_sum(v0 + v1) * (1.0f / 96.0f);
        const float d0 = v0 - mu;
        const float d1 = (lane < 32) ? (v1 - mu) : 0.0f;
        const float var = wave_reduce_sum(d0 * d0 + d1 * d1) * (1.0f / 96.0f);
        const float rstd = rsqrtf(var + EPS_LN);
        s_h[n * 104 + lane] = f2bf(d0 * rstd * g2[lane] + b2[lane]);
        if (lane < 32) s_h[n * 104 + 64 + lane] = f2bf(d1 * rstd * g2[64 + lane] + b2[64 + lane]);
    }
    __syncthreads();

    // FC1 + exact GELU -> s_g
#pragma unroll 1
    for (int i = 0; i < 12; ++i) {
        const int nt = nh * 12 + i;
        f32x4 acc = {0.f, 0.f, 0.f, 0.f};
#pragma unroll
        for (int ks = 0; ks < 3; ++ks) {
            s16x8 a = *(const s16x8*)(&s_h[(mt * 16 + c16) * 104 + ks * 32 + g4 * 8]);
            s16x8 bw = *(const s16x8*)(w1 + (size_t)(nt * 16 + c16) * 96 + ks * 32 + g4 * 8);
            acc = __builtin_amdgcn_mfma_f32_16x16x32_bf16(a, bw, acc, 0, 0, 0);
        }
        const int col = nt * 16 + c16;
        const float bias = fc1_b[col];
#pragma unroll
        for (int r = 0; r < 4; ++r) {
            const float v = acc[r] + bias;
            const float gelu = 0.5f * v * (1.0f + erff(v * 0.70710678118654752f));
            s_g[(mt * 16 + g4 * 4 + r) * 392 + col] = f2bf(gelu);
        }
    }
    __syncthreads();

    // FC2 + bias + residual -> s_res (f32)
#pragma unroll 1
    for (int i = 0; i < 3; ++i) {
        const int nt = nh * 3 + i;
        f32x4 acc = {0.f, 0.f, 0.f, 0.f};
#pragma unroll
        for (int ks = 0; ks < 12; ++ks) {
            s16x8 a = *(const s16x8*)(&s_g[(mt * 16 + c16) * 392 + ks * 32 + g4 * 8]);
            s16x8 bw = *(const s16x8*)(w2 + (size_t)(nt * 16 + c16) * 384 + ks * 32 + g4 * 8);
            acc = __builtin_amdgcn_mfma_f32_16x16x32_bf16(a, bw, acc, 0, 0, 0);
        }
        const int col = nt * 16 + c16;
        const float bias = fc2_b[col];
#pragma unroll
        for (int r = 0; r < 4; ++r) {
            const int row = mt * 16 + g4 * 4 + r;
            s_res[row * 100 + col] = acc[r] + bias + xl2[(size_t)(t0 + row) * C_DIM + col];
        }
    }
    __syncthreads();

    // transposed write: out[(b, c, s)]
    const int bb = t0 / SPATIAL;
    const int sbase = t0 % SPATIAL;
    for (int idx = tid; idx < 96 * 32; idx += 256) {
        const int c = idx >> 5, tok = idx & 31;
        out[((size_t)bb * C_DIM + c) * SPATIAL + sbase + tok] = s_res[tok * 100 + c];
    }
}

extern "C" void kernel_launch(void* const* d_in, const int* in_sizes, int n_in,
                              void* d_out, int out_size, void* d_ws, size_t ws_size,
                              hipStream_t stream) {
    const float* x      = (const float*)d_in[0];
    const float* g1     = (const float*)d_in[1];
    const float* be1    = (const float*)d_in[2];
    const float* g2     = (const float*)d_in[3];
    const float* be2    = (const float*)d_in[4];
    const float* qkv_w  = (const float*)d_in[5];
    const float* qkv_b  = (const float*)d_in[6];
    const float* proj_w = (const float*)d_in[7];
    const float* proj_b = (const float*)d_in[8];
    const float* rpb    = (const float*)d_in[9];
    const float* fc1_w  = (const float*)d_in[10];
    const float* fc1_b  = (const float*)d_in[11];
    const float* fc2_w  = (const float*)d_in[12];
    const float* fc2_b  = (const float*)d_in[13];
    float* out = (float*)d_out;

    float* xl  = (float*)d_ws;
    float* xl2 = xl + (size_t)NTOK * C_DIM;
    u16* wq = (u16*)(xl2 + (size_t)NTOK * C_DIM);
    u16* wp = wq + 27648;
    u16* w1 = wp + 9216;
    u16* w2 = w1 + 36864;
    float* rpbm = (float*)(w2 + 36864);

    k_prep<<<688, 256, 0, stream>>>(qkv_w, proj_w, fc1_w, fc2_w, rpb, wq, wp, w1, w2, rpbm);
    k_transpose_in<<<dim3(SPATIAL / 32, C_DIM / 32, BATCH), dim3(32, 8), 0, stream>>>(x, xl);
    k_win_attn<<<NWIN_TOT, 512, 0, stream>>>(xl, xl2, g1, be1, wq, qkv_b, wp, proj_b, rpbm);
    k_ffn<<<NTOK / 32, 256, 0, stream>>>(xl2, out, g2, be2, w1, fc1_b, w2, fc2_b);
}